// Round 1
// baseline (153.470 us; speedup 1.0000x reference)
//
#include <hip/hip_runtime.h>
#include <hip/hip_bf16.h>

#define NBLK 8
#define DIN 512
#define DOUT 512
#define NFEAT 4096      // NBLK * DIN
#define BATCH 8192
#define BM 128
#define BN 128
#define BK 32
#define LDK 40          // padded LDS row length (bf16 elems): 80 B = 20 banks, odd stride

typedef __attribute__((ext_vector_type(8))) short short8;
typedef __attribute__((ext_vector_type(4))) float f32x4;

__device__ __forceinline__ short f2bf16(float f) {
  __bf16 h = (__bf16)f;               // RNE convert; compiler packs pairs into v_cvt_pk_bf16_f32
  return __builtin_bit_cast(short, h);
}

__global__ __launch_bounds__(256) void blocklinear_kernel(
    const float* __restrict__ x, const float* __restrict__ W,
    const float* __restrict__ bias, float* __restrict__ y)
{
  // grid: 8 blocks * 64 m-tiles * 4 n-tiles = 2048; n-tiles innermost for L2 x-panel reuse
  const int idx = blockIdx.x;
  const int nb  = idx >> 8;
  const int rem = idx & 255;
  const int mt  = rem >> 2;
  const int nt  = rem & 3;

  const int tid  = threadIdx.x;
  const int lane = tid & 63;
  const int wid  = tid >> 6;   // 0..3
  const int wr   = wid >> 1;   // wave row (0..1)
  const int wc   = wid & 1;    // wave col (0..1)
  const int l15  = lane & 15;
  const int k16  = lane >> 4;  // 0..3

  __shared__ short lds[2][2][BM * LDK];   // [dbuf][A=0/B=1][row*LDK+col], 40 KiB

  // staging: thread t loads row r = t>>1, 16-float half = t&1  (128 rows x 32 cols fp32)
  const int r    = tid >> 1;
  const int half = tid & 1;

  const float* ap = x + (size_t)(mt * BM + r) * NFEAT + nb * DIN + half * 16;
  const float* bp = W + (size_t)nb * DOUT * DIN + (size_t)(nt * BN + r) * DIN + half * 16;

  f32x4 acc[4][4];
#pragma unroll
  for (int m = 0; m < 4; ++m)
#pragma unroll
    for (int n = 0; n < 4; ++n)
      acc[m][n] = (f32x4){0.f, 0.f, 0.f, 0.f};

  f32x4 areg[4], breg[4];

#define LOAD_TILE(t)                                        \
  {                                                         \
    const float* a_ = ap + (t) * BK;                        \
    const float* b_ = bp + (t) * BK;                        \
    _Pragma("unroll")                                       \
    for (int i = 0; i < 4; ++i) {                           \
      areg[i] = *(const f32x4*)(a_ + i * 4);                \
      breg[i] = *(const f32x4*)(b_ + i * 4);                \
    }                                                       \
  }

#define WRITE_TILE(buf)                                     \
  {                                                         \
    short sa[16], sb[16];                                   \
    _Pragma("unroll")                                       \
    for (int i = 0; i < 4; ++i)                             \
      _Pragma("unroll")                                     \
      for (int j = 0; j < 4; ++j) {                         \
        sa[i * 4 + j] = f2bf16(areg[i][j]);                 \
        sb[i * 4 + j] = f2bf16(breg[i][j]);                 \
      }                                                     \
    short* la = &lds[buf][0][r * LDK + half * 16];          \
    short* lb = &lds[buf][1][r * LDK + half * 16];          \
    *(short8*)(la)     = *(short8*)(sa);                    \
    *(short8*)(la + 8) = *(short8*)(sa + 8);                \
    *(short8*)(lb)     = *(short8*)(sb);                    \
    *(short8*)(lb + 8) = *(short8*)(sb + 8);                \
  }

#define COMPUTE(buf)                                                            \
  {                                                                             \
    const short* la = &lds[buf][0][0];                                          \
    const short* lb = &lds[buf][1][0];                                          \
    short8 af[4], bf[4];                                                        \
    _Pragma("unroll")                                                           \
    for (int m = 0; m < 4; ++m)                                                 \
      af[m] = *(const short8*)(la + (wr * 64 + m * 16 + l15) * LDK + k16 * 8);  \
    _Pragma("unroll")                                                           \
    for (int n = 0; n < 4; ++n)                                                 \
      bf[n] = *(const short8*)(lb + (wc * 64 + n * 16 + l15) * LDK + k16 * 8);  \
    _Pragma("unroll")                                                           \
    for (int m = 0; m < 4; ++m)                                                 \
      _Pragma("unroll")                                                         \
      for (int n = 0; n < 4; ++n)                                               \
        acc[m][n] = __builtin_amdgcn_mfma_f32_16x16x32_bf16(af[m], bf[n], acc[m][n], 0, 0, 0); \
  }

  LOAD_TILE(0);
  WRITE_TILE(0);
  __syncthreads();

  const int NT = DIN / BK;   // 16
#pragma unroll 2
  for (int t = 0; t < NT; ++t) {
    const int cur = t & 1;
    if (t + 1 < NT) LOAD_TILE(t + 1);     // issue early: HBM latency hides under MFMA
    COMPUTE(cur);
    if (t + 1 < NT) WRITE_TILE(cur ^ 1);  // write-late into the other buffer
    __syncthreads();                      // one barrier per K-step
  }

  // epilogue: C/D layout col=lane&15, row=(lane>>4)*4+j  [m89-verified]
  const int col0 = nt * BN + wc * 64;
  const int row0 = mt * BM + wr * 64;
  const float* bptr = bias + nb * DOUT + col0;
#pragma unroll
  for (int n = 0; n < 4; ++n) {
    const float bv = bptr[n * 16 + l15];
    const size_t col = (size_t)nb * DOUT + col0 + n * 16 + l15;
#pragma unroll
    for (int m = 0; m < 4; ++m) {
      const int row = row0 + m * 16 + k16 * 4;
      float* yp = y + (size_t)row * NFEAT + col;
#pragma unroll
      for (int j = 0; j < 4; ++j)
        yp[(size_t)j * NFEAT] = acc[m][n][j] + bv;
    }
  }
}

extern "C" void kernel_launch(void* const* d_in, const int* in_sizes, int n_in,
                              void* d_out, int out_size, void* d_ws, size_t ws_size,
                              hipStream_t stream) {
  const float* x = (const float*)d_in[0];
  const float* W = (const float*)d_in[1];
  const float* b = (const float*)d_in[2];
  float* y = (float*)d_out;
  const int grid = NBLK * (BATCH / BM) * (DOUT / BN);  // 2048
  blocklinear_kernel<<<grid, 256, 0, stream>>>(x, W, b, y);
}

// Round 2
// 102.105 us; speedup vs baseline: 1.5031x; 1.5031x over previous
//
#include <hip/hip_runtime.h>
#include <hip/hip_bf16.h>

#define NBLK 8
#define DIN 512
#define DOUT 512
#define NFEAT 4096      // NBLK * DIN
#define BATCH 8192
#define BM 128
#define BN 128
#define BK 32
#define NT 16           // DIN / BK

typedef __attribute__((ext_vector_type(8))) short short8;
typedef __attribute__((ext_vector_type(4))) float f32x4;

__device__ __forceinline__ short f2bf16(float f) {
  __bf16 h = (__bf16)f;               // RNE; compiler packs pairs into v_cvt_pk_bf16_f32
  return __builtin_bit_cast(short, h);
}

__global__ __launch_bounds__(256) void blocklinear_kernel(
    const float* __restrict__ x, const float* __restrict__ W,
    const float* __restrict__ bias, float* __restrict__ y)
{
  // XCD swizzle (bijective: 2048 % 8 == 0). HW assigns block b -> XCD b%8;
  // logical id groups one nb per XCD so nt-siblings share x-panels in L2.
  const int b       = blockIdx.x;
  const int logical = (b & 7) * 256 + (b >> 3);
  const int nb  = logical >> 8;
  const int rem = logical & 255;
  const int mt  = rem >> 2;
  const int nt  = rem & 3;   // innermost: 4 nt-siblings co-resident share x panel

  const int tid  = threadIdx.x;
  const int lane = tid & 63;
  const int wid  = tid >> 6;   // 0..3
  const int wr   = wid >> 1;   // wave row
  const int wc   = wid & 1;    // wave col
  const int l15  = lane & 15;
  const int k16  = lane >> 4;  // 0..3

  // 32 KiB total -> 5 blocks/CU LDS ceiling. XOR-swizzled 16B chunks:
  // chunk' = chunk ^ ((row>>1)&3). Reads and writes both land 8 lanes per
  // 4-bank slot -> conflict-free at the data-volume limit.
  __shared__ short lds[2][2][BM * BK];

  const int r = tid >> 1;      // staged row 0..127
  const int h = tid & 1;       // 16-float half
  const int q = (r >> 1) & 3;  // write-side swizzle key (loop-invariant)
  const int wa0 = r * BK + (((2 * h)     ^ q) * 8);
  const int wa1 = r * BK + (((2 * h + 1) ^ q) * 8);
  const int swz = (l15 >> 1) & 3;  // read-side swizzle key (loop-invariant)
  const int ra_off = (wr * 64 + l15) * BK + ((k16 ^ swz) * 8);
  const int rb_off = (wc * 64 + l15) * BK + ((k16 ^ swz) * 8);

  const float* ap = x + (size_t)(mt * BM + r) * NFEAT + nb * DIN + h * 16;
  const float* bp = W + (size_t)nb * DOUT * DIN + (size_t)(nt * BN + r) * DIN + h * 16;

  f32x4 acc[4][4];
#pragma unroll
  for (int m = 0; m < 4; ++m)
#pragma unroll
    for (int n = 0; n < 4; ++n)
      acc[m][n] = (f32x4){0.f, 0.f, 0.f, 0.f};

  // two named staging sets (static indexing only — rule #20)
  f32x4 ra0[4], rb0[4], ra1[4], rb1[4];

#define LOAD_T(RA, RB, t)                                   \
  {                                                         \
    _Pragma("unroll")                                       \
    for (int i = 0; i < 4; ++i) {                           \
      RA[i] = *(const f32x4*)(ap + (t) * BK + i * 4);       \
      RB[i] = *(const f32x4*)(bp + (t) * BK + i * 4);       \
    }                                                       \
  }

#define WRITE_T(RA, RB, buf)                                \
  {                                                         \
    short sa[16], sb[16];                                   \
    _Pragma("unroll")                                       \
    for (int i = 0; i < 4; ++i)                             \
      _Pragma("unroll")                                     \
      for (int j = 0; j < 4; ++j) {                         \
        sa[i * 4 + j] = f2bf16(RA[i][j]);                   \
        sb[i * 4 + j] = f2bf16(RB[i][j]);                   \
      }                                                     \
    *(short8*)&lds[buf][0][wa0] = *(short8*)(sa);           \
    *(short8*)&lds[buf][0][wa1] = *(short8*)(sa + 8);       \
    *(short8*)&lds[buf][1][wa0] = *(short8*)(sb);           \
    *(short8*)&lds[buf][1][wa1] = *(short8*)(sb + 8);       \
  }

#define COMPUTE(buf)                                                           \
  {                                                                            \
    short8 af[4], bf[4];                                                       \
    _Pragma("unroll")                                                          \
    for (int m = 0; m < 4; ++m)                                                \
      af[m] = *(const short8*)&lds[buf][0][ra_off + m * 16 * BK];              \
    _Pragma("unroll")                                                          \
    for (int n = 0; n < 4; ++n)                                                \
      bf[n] = *(const short8*)&lds[buf][1][rb_off + n * 16 * BK];              \
    _Pragma("unroll")                                                          \
    for (int m = 0; m < 4; ++m)                                                \
      _Pragma("unroll")                                                        \
      for (int n = 0; n < 4; ++n)                                              \
        acc[m][n] = __builtin_amdgcn_mfma_f32_16x16x32_bf16(af[m], bf[n], acc[m][n], 0, 0, 0); \
  }

  // prologue: tile0 staged; tile1 in flight
  LOAD_T(ra0, rb0, 0);
  WRITE_T(ra0, rb0, 0);
  LOAD_T(ra1, rb1, 1);
  __syncthreads();

  // steady state: loads for tile t+2 issue at iter t, LDS-write at iter t+1
  // -> one full iteration (+barrier) of latency cover per load.
#pragma unroll
  for (int tt = 0; tt < NT; tt += 2) {
    // even step t = tt (buf0)
    if (tt + 2 < NT) LOAD_T(ra0, rb0, tt + 2);
    COMPUTE(0);
    WRITE_T(ra1, rb1, 1);
    __syncthreads();
    // odd step t = tt+1 (buf1)
    if (tt + 3 < NT) LOAD_T(ra1, rb1, tt + 3);
    COMPUTE(1);
    if (tt + 2 < NT) WRITE_T(ra0, rb0, 0);
    __syncthreads();
  }

  // epilogue: C/D layout col = lane&15, row = (lane>>4)*4 + j  [m89-verified]
  const int col0 = nt * BN + wc * 64;
  const int row0 = mt * BM + wr * 64;
  const float* bptr = bias + nb * DOUT + col0;
#pragma unroll
  for (int n = 0; n < 4; ++n) {
    const float bv = bptr[n * 16 + l15];
    const size_t col = (size_t)nb * DOUT + col0 + n * 16 + l15;
#pragma unroll
    for (int m = 0; m < 4; ++m) {
      const int row = row0 + m * 16 + k16 * 4;
      float* yp = y + (size_t)row * NFEAT + col;
#pragma unroll
      for (int j = 0; j < 4; ++j)
        yp[(size_t)j * NFEAT] = acc[m][n][j] + bv;
    }
  }
}

extern "C" void kernel_launch(void* const* d_in, const int* in_sizes, int n_in,
                              void* d_out, int out_size, void* d_ws, size_t ws_size,
                              hipStream_t stream) {
  const float* x = (const float*)d_in[0];
  const float* W = (const float*)d_in[1];
  const float* b = (const float*)d_in[2];
  float* y = (float*)d_out;
  const int grid = NBLK * (BATCH / BM) * (DOUT / BN);  // 2048
  blocklinear_kernel<<<grid, 256, 0, stream>>>(x, W, b, y);
}